// Round 9
// baseline (91.585 us; speedup 1.0000x reference)
//
#include <hip/hip_runtime.h>

#define IMG_H 512
#define IMG_W 512
#define N_IMG 24                          // B*C
#define NPIX (N_IMG * IMG_H * IMG_W)      // 6291456
#define ROWS_PB 8                         // output rows per tile
#define SROWS 10                          // staged rows per tile (dy>=0 only)
#define LDSW 520                          // 2 halo + 512 + 2 halo + pad (16B stride)
#define BLOCK 256
#define NBLK 768                          // 3 blocks/CU exactly -> ONE generation
// each block owns a vertical PAIR of tiles: 16 output rows

// Partial vmem wait + hard scheduler fence.
#define VMWAIT(N)                                             \
    asm volatile("s_waitcnt vmcnt(" #N ")" ::: "memory");     \
    __builtin_amdgcn_sched_barrier(0)

// Branchless reflect for PAD=2 rows: min(|x|, 2H-2-|x|)
__device__ __forceinline__ int reflect_b(int x) {
    int a = x < 0 ? -x : x;
    int b = 2 * IMG_H - 2 - a;
    return a < b ? a : b;
}

// Raw loads via volatile asm: pinned issue point, NO compiler waitcnt —
// program-ordered against VMWAIT; stay outstanding across barriers.
__device__ __forceinline__ float4 gload4(const float* p) {
    float4 r;
    asm volatile("global_load_dwordx4 %0, %1, off" : "=v"(r) : "v"(p));
    return r;
}
__device__ __forceinline__ float gload1(const float* p) {
    float r;
    asm volatile("global_load_dword %0, %1, off" : "=v"(r) : "v"(p));
    return r;
}

// Load one window row (8 floats per input) from LDS; 16B-aligned
// ds_read_b128, lane stride 16B -> conflict-free.
#define ROW_LD(K)                                                      \
    {                                                                  \
        const int r_ = sl4 + (K);                                      \
        const float4 a_ = *(const float4*)&lds[0][r_][c4];             \
        const float4 b_ = *(const float4*)&lds[0][r_][c4 + 4];         \
        pw[K][0] = a_.x; pw[K][1] = a_.y; pw[K][2] = a_.z; pw[K][3] = a_.w; \
        pw[K][4] = b_.x; pw[K][5] = b_.y; pw[K][6] = b_.z; pw[K][7] = b_.w; \
        const float4 c_ = *(const float4*)&lds[1][r_][c4];             \
        const float4 d_ = *(const float4*)&lds[1][r_][c4 + 4];         \
        gw[K][0] = c_.x; gw[K][1] = c_.y; gw[K][2] = c_.z; gw[K][3] = c_.w; \
        gw[K][4] = d_.x; gw[K][5] = d_.y; gw[K][6] = d_.z; gw[K][7] = d_.w; \
    }

// Symmetry-halved census (proven EXACT in round 7: absmax 0.0): only the 12
// lexicographically-positive offsets; final mean doubles the count.
#define DO_ROW(R)                                                              \
    {                                                                          \
        const float pc0 = pw[R][2], pc1 = pw[R][3],                            \
                    pc2 = pw[R][4], pc3 = pw[R][5];                            \
        const float gc0 = gw[R][2], gc1 = gw[R][3],                            \
                    gc2 = gw[R][4], gc3 = gw[R][5];                            \
        _Pragma("unroll")                                                      \
        for (int dx = 1; dx <= 2; ++dx) {                                      \
            c0 += (int)((pw[R][2 + dx] < pc0) != (gw[R][2 + dx] < gc0));       \
            c1 += (int)((pw[R][3 + dx] < pc1) != (gw[R][3 + dx] < gc1));       \
            c2 += (int)((pw[R][4 + dx] < pc2) != (gw[R][4 + dx] < gc2));       \
            c3 += (int)((pw[R][5 + dx] < pc3) != (gw[R][5 + dx] < gc3));       \
        }                                                                      \
        _Pragma("unroll")                                                      \
        for (int dy = 1; dy <= 2; ++dy) {                                      \
            const int row = (R) + dy;                                          \
            _Pragma("unroll")                                                  \
            for (int dx = 0; dx < 5; ++dx) {                                   \
                c0 += (int)((pw[row][0 + dx] < pc0) != (gw[row][0 + dx] < gc0)); \
                c1 += (int)((pw[row][1 + dx] < pc1) != (gw[row][1 + dx] < gc1)); \
                c2 += (int)((pw[row][2 + dx] < pc2) != (gw[row][2 + dx] < gc2)); \
                c3 += (int)((pw[row][3 + dx] < pc3) != (gw[row][3 + dx] < gc3)); \
            }                                                                  \
        }                                                                      \
    }

#define COMPUTE_TILE()                                                 \
    {                                                                  \
        ROW_LD(0) ROW_LD(1) ROW_LD(2)                                  \
        DO_ROW(0)                                                      \
        ROW_LD(3) DO_ROW(1)                                            \
        ROW_LD(4) DO_ROW(2)                                            \
        ROW_LD(5) DO_ROW(3)                                            \
    }

#define LDS_WRITE_TILE(P, G)                                           \
    _Pragma("unroll")                                                  \
    for (int i = 0; i < 5; ++i) {                                      \
        const int lr = rg + 2 * i;                                     \
        *(float2*)&lds[0][lr][2 + 4 * q] = make_float2(P[i].x, P[i].y);\
        *(float2*)&lds[0][lr][4 + 4 * q] = make_float2(P[i].z, P[i].w);\
        *(float2*)&lds[1][lr][2 + 4 * q] = make_float2(G[i].x, G[i].y);\
        *(float2*)&lds[1][lr][4 + 4 * q] = make_float2(G[i].z, G[i].w);\
    }

__global__ __launch_bounds__(BLOCK, 3) void census_main(
    const float* __restrict__ pred, const float* __restrict__ gt,
    unsigned int* __restrict__ ws)
{
    // XCD-chunked swizzle over the 768 pairs (768 % 8 == 0): vertically
    // adjacent pairs share halo rows on the same XCD's L2.
    const int b   = blockIdx.x;
    const int n   = (b & 7) * (NBLK / 8) + (b >> 3);
    const int img = n >> 5;                     // 24 images x 32 pairs
    const int h0  = (n & 31) * (2 * ROWS_PB);   // pair covers rows h0..h0+15
    const int h1  = h0 + ROWS_PB;

    const float* __restrict__ pimg = pred + (size_t)img * IMG_H * IMG_W;
    const float* __restrict__ gimg = gt   + (size_t)img * IMG_H * IMG_W;

    __shared__ float lds[2][SROWS][LDSW];   // 41,600 B -> 3 blocks/CU

    const int q  = threadIdx.x & 127;       // col quad for staging
    const int rg = threadIdx.x >> 7;        // row parity for staging

    // Halo parameters — ALL threads issue the halo loads (uniform per-wave
    // vmcnt, so partial VMWAIT counts are exact); only tid<80 write LDS.
    const bool hact = (threadIdx.x < 80);
    const int  hr   = hact ? (threadIdx.x >> 3) : 0;        // 0..9
    const int  hi   = hact ? ((threadIdx.x >> 2) & 1) : 0;  // input
    const int  hc   = threadIdx.x & 3;
    const int  hsrc = hact ? ((hc == 0) ? 2 : (hc == 1) ? 1 : (hc == 2) ? 510 : 509) : 2;
    const int  hdst = (hc == 0) ? 0 : (hc == 1) ? 1 : (hc == 2) ? 514 : 515;
    const float* hbase = hi ? gimg : pimg;

    // ---- ONE continuous burst: 22 vmem/thread, then partial wait ----
    // order: tile0 x10, halo0 x1, tile1 x10, halo1 x1
    float4 p0[5], g0[5], p1[5], g1[5];
    #pragma unroll
    for (int i = 0; i < 5; ++i) {
        const int gy = reflect_b(h0 + rg + 2 * i);
        p0[i] = gload4(pimg + (size_t)gy * IMG_W + 4 * q);
        g0[i] = gload4(gimg + (size_t)gy * IMG_W + 4 * q);
    }
    const float h0v = gload1(hbase + (size_t)reflect_b(h0 + hr) * IMG_W + hsrc);
    #pragma unroll
    for (int i = 0; i < 5; ++i) {
        const int gy = reflect_b(h1 + rg + 2 * i);
        p1[i] = gload4(pimg + (size_t)gy * IMG_W + 4 * q);
        g1[i] = gload4(gimg + (size_t)gy * IMG_W + 4 * q);
    }
    const float h1v = gload1(hbase + (size_t)reflect_b(h1 + hr) * IMG_W + hsrc);
    __builtin_amdgcn_sched_barrier(0);

    // tile0 + halo0 landed (11 newest = tile1 burst still in flight)
    VMWAIT(11);
    LDS_WRITE_TILE(p0, g0)
    if (hact) lds[hi][hr][hdst] = h0v;
    __syncthreads();

    // ---- compute tile 0 (tile-1 loads fly underneath) ----
    const int sc  = threadIdx.x & 127;
    const int sl  = threadIdx.x >> 7;
    const int c4  = 4 * sc;
    const int sl4 = 4 * sl;

    float pw[6][8], gw[6][8];
    int c0 = 0, c1 = 0, c2 = 0, c3 = 0;
    COMPUTE_TILE()

    __syncthreads();                        // everyone done READING tile 0

    VMWAIT(0);
    LDS_WRITE_TILE(p1, g1)
    if (hact) lds[hi][hr][hdst] = h1v;
    __syncthreads();

    // ---- compute tile 1 ----
    COMPUTE_TILE()

    int cnt = (c0 + c1) + (c2 + c3);

    // ---- block reduction (exact integer) ----
    #pragma unroll
    for (int off = 32; off > 0; off >>= 1)
        cnt += __shfl_down(cnt, off, 64);

    __shared__ int wave_sums[BLOCK / 64];
    const int lane = threadIdx.x & 63;
    const int wid  = threadIdx.x >> 6;
    if (lane == 0) wave_sums[wid] = cnt;
    __syncthreads();

    if (threadIdx.x == 0) {
        // Plain store to a distinct address (rounds 0/4/6: ANY same-line
        // RMW costs 10-60us; this is free).
        ws[blockIdx.x] = (unsigned int)(wave_sums[0] + wave_sums[1] +
                                        wave_sums[2] + wave_sums[3]);
    }
}

// Second pass: one block sums the 768 partials; mean doubles the count
// (each unordered pair counted once).
__global__ __launch_bounds__(BLOCK, 1) void census_reduce(
    const unsigned int* __restrict__ ws, float* __restrict__ out)
{
    unsigned int s = 0;
    #pragma unroll
    for (int i = 0; i < NBLK / BLOCK; ++i)         // 3 iterations
        s += ws[threadIdx.x + i * BLOCK];

    #pragma unroll
    for (int off = 32; off > 0; off >>= 1)
        s += __shfl_down(s, off, 64);

    __shared__ unsigned int wsum[BLOCK / 64];
    const int lane = threadIdx.x & 63;
    const int wid  = threadIdx.x >> 6;
    if (lane == 0) wsum[wid] = s;
    __syncthreads();

    if (threadIdx.x == 0) {
        unsigned int tot = wsum[0] + wsum[1] + wsum[2] + wsum[3];
        out[0] = (float)(2.0 * (double)tot / (double)NPIX);
    }
}

extern "C" void kernel_launch(void* const* d_in, const int* in_sizes, int n_in,
                              void* d_out, int out_size, void* d_ws, size_t ws_size,
                              hipStream_t stream) {
    const float* pred = (const float*)d_in[0];
    const float* gt   = (const float*)d_in[1];
    float* out        = (float*)d_out;
    unsigned int* ws  = (unsigned int*)d_ws;   // needs NBLK*4 = 3072 B

    census_main<<<NBLK, BLOCK, 0, stream>>>(pred, gt, ws);
    census_reduce<<<1, BLOCK, 0, stream>>>(ws, out);
}